// Round 2
// 150.525 us; speedup vs baseline: 1.0715x; 1.0715x over previous
//
#include <hip/hip_runtime.h>

#define T_SEQ 2048
#define NH 4
#define DH 64

typedef __bf16 bf16x8 __attribute__((ext_vector_type(8)));
typedef float f32x4 __attribute__((ext_vector_type(4)));
typedef unsigned short u16x8 __attribute__((ext_vector_type(8)));

__device__ __forceinline__ unsigned short f2bf_rne(float x) {
  unsigned int u = __builtin_bit_cast(unsigned int, x);
  u += 0x7fffu + ((u >> 16) & 1u);
  return (unsigned short)(u >> 16);
}

__device__ __forceinline__ void async_cp16(const unsigned short* g, unsigned short* l) {
  __builtin_amdgcn_global_load_lds(
      (const __attribute__((address_space(1))) unsigned int*)g,
      (__attribute__((address_space(3))) unsigned int*)l, 16, 0, 0);
}

// ---------------------------------------------------------------------------
// wprep: W (256x256 fp32, [k][n]) -> Wt ([n][k] bf16, hi plane + lo plane).
// Truncation split: hi = top16(w), lo = bf16(w - hi). Residual error ~2^-16.
// ---------------------------------------------------------------------------
__global__ __launch_bounds__(256) void wprep(const float* __restrict__ W,
                                             unsigned short* __restrict__ Wt) {
  int tid = blockIdx.x * 256 + threadIdx.x;  // 65536 elems
  int k = tid >> 8, n = tid & 255;
  float w = W[tid];  // W[k][n], coalesced read
  unsigned int u = __builtin_bit_cast(unsigned int, w);
  unsigned short hi = (unsigned short)(u >> 16);
  float fhi = __builtin_bit_cast(float, u & 0xffff0000u);
  float lo = w - fhi;
  Wt[n * 256 + k] = hi;
  Wt[65536 + n * 256 + k] =
      (unsigned short)(__builtin_bit_cast(unsigned int, lo) >> 16);
}

// ---------------------------------------------------------------------------
// wh_gemm v2: Wh = h @ W via bf16 MFMA with hi/lo split (fp32-level accuracy):
//   D = Ahi*Bhi + Ahi*Blo + Alo*Bhi   (drop Alo*Blo ~ 2^-16 rel)
// Block = 32 rows x 256 cols, 4 waves each 32 rows x 64 cols (head = wave).
// h tile (32KB fp32) is read by all 4 waves -> L1-resident; Wt L2-resident.
// Writes Kb[bh][t][d] = bf16(Wh * sqrt(log2e/8)),  Vt[bh][d][t] = bf16(Wh).
// ---------------------------------------------------------------------------
__global__ __launch_bounds__(256, 2) void wh_gemm(
    const float* __restrict__ h, const unsigned short* __restrict__ Wt,
    unsigned short* __restrict__ Kb, unsigned short* __restrict__ Vt) {
  const int tid = threadIdx.x;
  const int wave = tid >> 6;
  const int lane = tid & 63;
  const int l15 = lane & 15;
  const int quad = lane >> 4;
  const int mbase = blockIdx.x * 32;  // 512 blocks
  const int col0 = wave * 64;         // one head per wave

  f32x4 acc[2][4];
#pragma unroll
  for (int mt = 0; mt < 2; mt++)
#pragma unroll
    for (int nt = 0; nt < 4; nt++) acc[mt][nt] = (f32x4){0.f, 0.f, 0.f, 0.f};

  for (int ks = 0; ks < 8; ks++) {
    const int k0 = ks * 32 + quad * 8;
    // A-frags: A[m=l15][k=quad*8+j], fp32 from global, split hi/lo in regs
    bf16x8 ahi[2], alo[2];
#pragma unroll
    for (int mt = 0; mt < 2; mt++) {
      const float* hp = h + (size_t)(mbase + mt * 16 + l15) * 256 + k0;
      float xf[8];
      *(float4*)&xf[0] = *(const float4*)hp;
      *(float4*)&xf[4] = *(const float4*)(hp + 4);
      u16x8 hh, ll;
#pragma unroll
      for (int j = 0; j < 8; j++) {
        unsigned int u = __builtin_bit_cast(unsigned int, xf[j]);
        hh[j] = (unsigned short)(u >> 16);
        float lo = xf[j] - __builtin_bit_cast(float, u & 0xffff0000u);
        ll[j] = (unsigned short)(__builtin_bit_cast(unsigned int, lo) >> 16);
      }
      ahi[mt] = __builtin_bit_cast(bf16x8, hh);
      alo[mt] = __builtin_bit_cast(bf16x8, ll);
    }
    // B-frags: B[k=quad*8+j][n=l15] = Wt[col][k0+quad*8..+8], 16B/lane
#pragma unroll
    for (int nt = 0; nt < 4; nt++) {
      const unsigned short* wp = Wt + ((size_t)(col0 + nt * 16 + l15) << 8) + k0;
      bf16x8 bhi = *(const bf16x8*)wp;
      bf16x8 blo = *(const bf16x8*)(wp + 65536);
#pragma unroll
      for (int mt = 0; mt < 2; mt++) {
        acc[mt][nt] = __builtin_amdgcn_mfma_f32_16x16x32_bf16(ahi[mt], bhi, acc[mt][nt], 0, 0, 0);
        acc[mt][nt] = __builtin_amdgcn_mfma_f32_16x16x32_bf16(alo[mt], bhi, acc[mt][nt], 0, 0, 0);
        acc[mt][nt] = __builtin_amdgcn_mfma_f32_16x16x32_bf16(ahi[mt], blo, acc[mt][nt], 0, 0, 0);
      }
    }
  }

  // epilogue: C-layout row=quad*4+reg, col=l15
  const float s1 = 0.424664717f;  // sqrt(log2(e)/8)
#pragma unroll
  for (int mt = 0; mt < 2; mt++) {
    int row = mbase + mt * 16 + quad * 4;
    int b = row >> 11;
    int tb = row & 2047;
    size_t bh = (size_t)(b * NH + wave);
#pragma unroll
    for (int nt = 0; nt < 4; nt++) {
      int d = nt * 16 + l15;
      ushort4 vp;
#pragma unroll
      for (int r = 0; r < 4; r++) {
        float v = acc[mt][nt][r];
        Kb[(bh * T_SEQ + tb + r) * DH + d] = f2bf_rne(v * s1);
        ((unsigned short*)&vp)[r] = f2bf_rne(v);
      }
      *(ushort4*)&Vt[(bh * DH + d) * T_SEQ + tb] = vp;  // 4 consecutive t
    }
  }
}

// ---------------------------------------------------------------------------
// attn: per block = one (bh, 64-row q-tile). 4 waves, 16 q-rows/wave.
// v2: double-buffered K/V LDS + counted vmcnt (T3+T4) -- prefetch next tile
// at loop top, raw s_barrier with s_waitcnt vmcnt(4) so the 4 in-flight
// global_load_lds cross the barrier; latency hides under compute.
// setprio(1) around MFMA clusters (T5); bijective XCD swizzle (T1).
// ---------------------------------------------------------------------------
__global__ __launch_bounds__(256, 4) void attn(
    const unsigned short* __restrict__ Kb, const unsigned short* __restrict__ Vt,
    float* __restrict__ out) {
  __shared__ __align__(16) unsigned short ldsK[2][64 * 64];  // [buf][key][chunk-swz]
  __shared__ __align__(16) unsigned short ldsV[2][64 * 64];  // [buf][d][chunk-swz]
  __shared__ __align__(16) unsigned short ldsP[4][16 * 64];  // per-wave P
  const int tid = threadIdx.x;
  const int wave = tid >> 6;
  const int lane = tid & 63;
  const int l15 = lane & 15;
  const int quad = lane >> 4;
  // XCD swizzle: 1024 wgs, 8 XCDs -> 128 consecutive logical blocks (4 bh)
  // per XCD; 2MB K/V working set fits the 4MB per-XCD L2.
  const int lbid = (blockIdx.x & 7) * 128 + (blockIdx.x >> 3);
  const int bh = lbid >> 5;
  const int qtile = lbid & 31;
  const unsigned short* Kbh = Kb + (size_t)bh * T_SEQ * DH;
  const unsigned short* Vbh = Vt + (size_t)bh * DH * T_SEQ;

  // A-frag Q: A[m=lane&15][k=quad*8+j], two 32-wide k-steps over D=64
  const int qrow = qtile * 64 + wave * 16 + l15;
  bf16x8 aq0 = *(const bf16x8*)&Kbh[qrow * DH + quad * 8];
  bf16x8 aq1 = *(const bf16x8*)&Kbh[qrow * DH + 32 + quad * 8];

  f32x4 o[4];
  float lsum[4];
#pragma unroll
  for (int i = 0; i < 4; i++) {
    o[i] = (f32x4){0.f, 0.f, 0.f, 0.f};
    lsum[i] = 0.f;
  }
  unsigned short* Pw = ldsP[wave];

  auto stage = [&](int t, int buf) {
#pragma unroll
    for (int i = 0; i < 2; i++) {
      int slot = i * 256 + tid;          // 512 16B-slots per tile
      int r = slot >> 3;                 // row (key or d)
      int c = (slot & 7) ^ (r & 7);      // source chunk for swizzled slot
      async_cp16(&Kbh[(t * 64 + r) * DH + c * 8],
                 &ldsK[buf][(i * 256 + wave * 64) * 8]);  // wave-uniform base
      async_cp16(&Vbh[(size_t)r * T_SEQ + t * 64 + c * 8],
                 &ldsV[buf][(i * 256 + wave * 64) * 8]);
    }
  };

  stage(0, 0);  // prologue

  for (int kt = 0; kt < 32; kt++) {
    const int cur = kt & 1;
    if (kt < 31) {
      stage(kt + 1, cur ^ 1);                        // 4 loads -> in flight
      asm volatile("s_waitcnt vmcnt(4)" ::: "memory");  // tile kt landed
    } else {
      asm volatile("s_waitcnt vmcnt(0)" ::: "memory");
    }
    __builtin_amdgcn_s_barrier();  // all waves' buf[cur] staged
    __builtin_amdgcn_sched_barrier(0);

    const unsigned short* Kl = ldsK[cur];
    const unsigned short* Vl = ldsV[cur];

    // S = Q K^T : B-frag B[k=quad*8+j][n=key(lane&15)] from swizzled ldsK
    f32x4 sfr[4];
    __builtin_amdgcn_s_setprio(1);
#pragma unroll
    for (int nt = 0; nt < 4; nt++) {
      int key = nt * 16 + l15;
      bf16x8 kf0 = *(const bf16x8*)&Kl[key * 64 + ((quad ^ (key & 7)) << 3)];
      bf16x8 kf1 = *(const bf16x8*)&Kl[key * 64 + (((4 + quad) ^ (key & 7)) << 3)];
      f32x4 s = {0.f, 0.f, 0.f, 0.f};
      s = __builtin_amdgcn_mfma_f32_16x16x32_bf16(aq0, kf0, s, 0, 0, 0);
      s = __builtin_amdgcn_mfma_f32_16x16x32_bf16(aq1, kf1, s, 0, 0, 0);
      sfr[nt] = s;
    }
    __builtin_amdgcn_s_setprio(0);

    // p = exp2(leaky(S)) (scale pre-folded); accumulate l; P -> LDS (trunc bf16)
#pragma unroll
    for (int nt = 0; nt < 4; nt++) {
      int col = nt * 16 + l15;
#pragma unroll
      for (int reg = 0; reg < 4; reg++) {
        float v = sfr[nt][reg];
        float e = __builtin_amdgcn_exp2f(fmaxf(v, 0.2f * v));
        lsum[reg] += e;
        int row = quad * 4 + reg;  // C-layout: row=(lane>>4)*4+reg, col=lane&15
        Pw[(row << 6) + (((((col >> 3) ^ (row & 7))) << 3) | (col & 7))] =
            (unsigned short)(__builtin_bit_cast(unsigned int, e) >> 16);
      }
    }
    __builtin_amdgcn_s_waitcnt(0xC07F);  // lgkmcnt(0): P writes land before reads

    // O += P V : A-frag from Pw round-trip, B-frag from swizzled ldsV
    __builtin_amdgcn_s_setprio(1);
#pragma unroll
    for (int kc = 0; kc < 2; kc++) {
      bf16x8 ap = *(const bf16x8*)&Pw[(l15 << 6) + ((((kc << 2) + quad) ^ (l15 & 7)) << 3)];
#pragma unroll
      for (int nt = 0; nt < 4; nt++) {
        int d = nt * 16 + l15;
        bf16x8 vf = *(const bf16x8*)&Vl[(d << 6) + ((((kc << 2) + quad) ^ (d & 7)) << 3)];
        o[nt] = __builtin_amdgcn_mfma_f32_16x16x32_bf16(ap, vf, o[nt], 0, 0, 0);
      }
    }
    __builtin_amdgcn_s_setprio(0);
    __builtin_amdgcn_sched_barrier(0);
    __builtin_amdgcn_s_barrier();  // buf[cur] reads done -> next stage may overwrite
  }

  // epilogue: reduce l across the 16 lanes sharing each row group, normalize
  float inv[4];
#pragma unroll
  for (int reg = 0; reg < 4; reg++) {
    float l = lsum[reg];
    l += __shfl_xor(l, 1, 64);
    l += __shfl_xor(l, 2, 64);
    l += __shfl_xor(l, 4, 64);
    l += __shfl_xor(l, 8, 64);
    inv[reg] = 1.0f / l;
  }
  const int b = bh >> 2, head = bh & 3;
#pragma unroll
  for (int nt = 0; nt < 4; nt++) {
    int d = nt * 16 + l15;
#pragma unroll
    for (int reg = 0; reg < 4; reg++) {
      int trow = qtile * 64 + wave * 16 + quad * 4 + reg;
      out[((size_t)b * T_SEQ + trow) * 256 + head * 64 + d] = o[nt][reg] * inv[reg];
    }
  }
}

extern "C" void kernel_launch(void* const* d_in, const int* in_sizes, int n_in,
                              void* d_out, int out_size, void* d_ws, size_t ws_size,
                              hipStream_t stream) {
  const float* h = (const float*)d_in[0];
  const float* W = (const float*)d_in[1];
  float* out = (float*)d_out;
  // workspace: Kb 8 MB + Vt 8 MB + Wt 256 KB (hi/lo bf16 planes of W^T)
  unsigned short* Kb = (unsigned short*)d_ws;
  unsigned short* Vt = Kb + (size_t)32 * T_SEQ * DH;
  unsigned short* Wt = Vt + (size_t)32 * T_SEQ * DH;
  wprep<<<256, 256, 0, stream>>>(W, Wt);
  wh_gemm<<<512, 256, 0, stream>>>(h, Wt, Kb, Vt);
  attn<<<32 * 32, 256, 0, stream>>>(Kb, Vt, out);
}

// Round 3
// 147.816 us; speedup vs baseline: 1.0911x; 1.0183x over previous
//
#include <hip/hip_runtime.h>

#define T_SEQ 2048
#define NH 4
#define DH 64

typedef __bf16 bf16x8 __attribute__((ext_vector_type(8)));
typedef float f32x4 __attribute__((ext_vector_type(4)));
typedef unsigned short u16x8 __attribute__((ext_vector_type(8)));

__device__ __forceinline__ unsigned short f2bf_rne(float x) {
  unsigned int u = __builtin_bit_cast(unsigned int, x);
  u += 0x7fffu + ((u >> 16) & 1u);
  return (unsigned short)(u >> 16);
}

__device__ __forceinline__ void async_cp16(const unsigned short* g, unsigned short* l) {
  __builtin_amdgcn_global_load_lds(
      (const __attribute__((address_space(1))) unsigned int*)g,
      (__attribute__((address_space(3))) unsigned int*)l, 16, 0, 0);
}

// ---------------------------------------------------------------------------
// wprep: W (256x256 fp32, [k][n]) -> Wt ([n][k] bf16, hi plane + lo plane).
// Truncation split: hi = top16(w), lo = bf16(w - hi). Residual error ~2^-16.
// ---------------------------------------------------------------------------
__global__ __launch_bounds__(256) void wprep(const float* __restrict__ W,
                                             unsigned short* __restrict__ Wt) {
  int tid = blockIdx.x * 256 + threadIdx.x;  // 65536 elems
  int k = tid >> 8, n = tid & 255;
  float w = W[tid];  // W[k][n], coalesced read
  unsigned int u = __builtin_bit_cast(unsigned int, w);
  unsigned short hi = (unsigned short)(u >> 16);
  float fhi = __builtin_bit_cast(float, u & 0xffff0000u);
  float lo = w - fhi;
  Wt[n * 256 + k] = hi;
  Wt[65536 + n * 256 + k] =
      (unsigned short)(__builtin_bit_cast(unsigned int, lo) >> 16);
}

// ---------------------------------------------------------------------------
// wh_gemm v3: Wh = h @ W via bf16 MFMA hi/lo split (D = AhBh + AhBl + AlBh).
// v2 suspected scratch-spill (punned float arrays + unroll-hoisted loads).
// v3: h tile staged ONCE to LDS as pre-split bf16 hi/lo planes (chunk-XOR
// swizzle, 2-way = free); k-loop reads A via ds_read_b128, B via global b128
// (Wt is 256KB, L2-hot); #pragma unroll 2 bounds in-flight regs (~180 VGPR).
// Writes Kb[bh][t][d] = bf16(Wh * sqrt(log2e/8)),  Vt[bh][d][t] = bf16(Wh).
// ---------------------------------------------------------------------------
__global__ __launch_bounds__(256, 2) void wh_gemm(
    const float* __restrict__ h, const unsigned short* __restrict__ Wt,
    unsigned short* __restrict__ Kb, unsigned short* __restrict__ Vt) {
  __shared__ __align__(16) unsigned short Ahi[32 * 256];  // [row][chunk^row&7]
  __shared__ __align__(16) unsigned short Alo[32 * 256];
  const int tid = threadIdx.x;
  const int wave = tid >> 6;
  const int lane = tid & 63;
  const int l15 = lane & 15;
  const int quad = lane >> 4;
  const int mbase = blockIdx.x * 32;  // 512 blocks
  const int col0 = wave * 64;         // one head per wave

  // ---- stage h tile: thread t -> row t>>3, float cols (t&7)*32..+31 ----
  {
    const int r = tid >> 3;
    const int cbase = (tid & 7) * 4;  // 16B-chunk index base (chunk = 8 bf16)
    const float4* hp = (const float4*)(h + ((size_t)(mbase + r) << 8) + cbase * 8);
#pragma unroll
    for (int j = 0; j < 4; j++) {
      float4 f0 = hp[2 * j];
      float4 f1 = hp[2 * j + 1];
      u16x8 hi, lo;
#define SPLIT1(v, idx)                                                    \
  {                                                                       \
    unsigned int u_ = __builtin_bit_cast(unsigned int, (v));              \
    hi[idx] = (unsigned short)(u_ >> 16);                                 \
    float r_ = (v) - __builtin_bit_cast(float, u_ & 0xffff0000u);         \
    lo[idx] = (unsigned short)(__builtin_bit_cast(unsigned int, r_) >> 16); \
  }
      SPLIT1(f0.x, 0) SPLIT1(f0.y, 1) SPLIT1(f0.z, 2) SPLIT1(f0.w, 3)
      SPLIT1(f1.x, 4) SPLIT1(f1.y, 5) SPLIT1(f1.z, 6) SPLIT1(f1.w, 7)
#undef SPLIT1
      const int chunk = (cbase + j) ^ (r & 7);
      *(u16x8*)&Ahi[r * 256 + chunk * 8] = hi;
      *(u16x8*)&Alo[r * 256 + chunk * 8] = lo;
    }
  }
  __syncthreads();

  f32x4 acc[2][4];
#pragma unroll
  for (int mt = 0; mt < 2; mt++)
#pragma unroll
    for (int nt = 0; nt < 4; nt++) acc[mt][nt] = (f32x4){0.f, 0.f, 0.f, 0.f};

#pragma unroll 2
  for (int ks = 0; ks < 8; ks++) {
    const int k0 = ks * 32 + quad * 8;  // ushort offset within row
    // A-frags from LDS: A[m=l15][k=quad*8+j], chunk = k0>>3 = ks*4+quad
    bf16x8 ahi[2], alo[2];
#pragma unroll
    for (int mt = 0; mt < 2; mt++) {
      const int row = mt * 16 + l15;
      const int ch = (ks * 4 + quad) ^ (row & 7);
      ahi[mt] = *(const bf16x8*)&Ahi[row * 256 + ch * 8];
      alo[mt] = *(const bf16x8*)&Alo[row * 256 + ch * 8];
    }
    // B-frags from global (L2-hot): B[k=quad*8+j][n=l15]
#pragma unroll
    for (int nt = 0; nt < 4; nt++) {
      const unsigned short* wp = Wt + ((size_t)(col0 + nt * 16 + l15) << 8) + k0;
      bf16x8 bhi = *(const bf16x8*)wp;
      bf16x8 blo = *(const bf16x8*)(wp + 65536);
#pragma unroll
      for (int mt = 0; mt < 2; mt++) {
        acc[mt][nt] = __builtin_amdgcn_mfma_f32_16x16x32_bf16(ahi[mt], bhi, acc[mt][nt], 0, 0, 0);
        acc[mt][nt] = __builtin_amdgcn_mfma_f32_16x16x32_bf16(alo[mt], bhi, acc[mt][nt], 0, 0, 0);
        acc[mt][nt] = __builtin_amdgcn_mfma_f32_16x16x32_bf16(ahi[mt], blo, acc[mt][nt], 0, 0, 0);
      }
    }
  }

  // epilogue: C-layout row=quad*4+reg, col=l15
  const float s1 = 0.424664717f;  // sqrt(log2(e)/8)
#pragma unroll
  for (int mt = 0; mt < 2; mt++) {
    int row = mbase + mt * 16 + quad * 4;
    int b = row >> 11;
    int tb = row & 2047;
    size_t bh = (size_t)(b * NH + wave);
#pragma unroll
    for (int nt = 0; nt < 4; nt++) {
      int d = nt * 16 + l15;
      Kb[(bh * T_SEQ + tb + 0) * DH + d] = f2bf_rne(acc[mt][nt][0] * s1);
      Kb[(bh * T_SEQ + tb + 1) * DH + d] = f2bf_rne(acc[mt][nt][1] * s1);
      Kb[(bh * T_SEQ + tb + 2) * DH + d] = f2bf_rne(acc[mt][nt][2] * s1);
      Kb[(bh * T_SEQ + tb + 3) * DH + d] = f2bf_rne(acc[mt][nt][3] * s1);
      ushort4 vp;
      vp.x = f2bf_rne(acc[mt][nt][0]);
      vp.y = f2bf_rne(acc[mt][nt][1]);
      vp.z = f2bf_rne(acc[mt][nt][2]);
      vp.w = f2bf_rne(acc[mt][nt][3]);
      *(ushort4*)&Vt[(bh * DH + d) * T_SEQ + tb] = vp;  // 4 consecutive t
    }
  }
}

// ---------------------------------------------------------------------------
// attn: unchanged from round-2 (passed, 67.4us). Double-buffered K/V LDS +
// counted vmcnt, setprio around MFMA clusters, bijective XCD swizzle.
// ---------------------------------------------------------------------------
__global__ __launch_bounds__(256, 4) void attn(
    const unsigned short* __restrict__ Kb, const unsigned short* __restrict__ Vt,
    float* __restrict__ out) {
  __shared__ __align__(16) unsigned short ldsK[2][64 * 64];  // [buf][key][chunk-swz]
  __shared__ __align__(16) unsigned short ldsV[2][64 * 64];  // [buf][d][chunk-swz]
  __shared__ __align__(16) unsigned short ldsP[4][16 * 64];  // per-wave P
  const int tid = threadIdx.x;
  const int wave = tid >> 6;
  const int lane = tid & 63;
  const int l15 = lane & 15;
  const int quad = lane >> 4;
  // XCD swizzle: 1024 wgs, 8 XCDs -> 128 consecutive logical blocks (4 bh)
  // per XCD; 2MB K/V working set fits the 4MB per-XCD L2.
  const int lbid = (blockIdx.x & 7) * 128 + (blockIdx.x >> 3);
  const int bh = lbid >> 5;
  const int qtile = lbid & 31;
  const unsigned short* Kbh = Kb + (size_t)bh * T_SEQ * DH;
  const unsigned short* Vbh = Vt + (size_t)bh * DH * T_SEQ;

  // A-frag Q: A[m=lane&15][k=quad*8+j], two 32-wide k-steps over D=64
  const int qrow = qtile * 64 + wave * 16 + l15;
  bf16x8 aq0 = *(const bf16x8*)&Kbh[qrow * DH + quad * 8];
  bf16x8 aq1 = *(const bf16x8*)&Kbh[qrow * DH + 32 + quad * 8];

  f32x4 o[4];
  float lsum[4];
#pragma unroll
  for (int i = 0; i < 4; i++) {
    o[i] = (f32x4){0.f, 0.f, 0.f, 0.f};
    lsum[i] = 0.f;
  }
  unsigned short* Pw = ldsP[wave];

  auto stage = [&](int t, int buf) {
#pragma unroll
    for (int i = 0; i < 2; i++) {
      int slot = i * 256 + tid;          // 512 16B-slots per tile
      int r = slot >> 3;                 // row (key or d)
      int c = (slot & 7) ^ (r & 7);      // source chunk for swizzled slot
      async_cp16(&Kbh[(t * 64 + r) * DH + c * 8],
                 &ldsK[buf][(i * 256 + wave * 64) * 8]);  // wave-uniform base
      async_cp16(&Vbh[(size_t)r * T_SEQ + t * 64 + c * 8],
                 &ldsV[buf][(i * 256 + wave * 64) * 8]);
    }
  };

  stage(0, 0);  // prologue

  for (int kt = 0; kt < 32; kt++) {
    const int cur = kt & 1;
    if (kt < 31) {
      stage(kt + 1, cur ^ 1);                        // 4 loads -> in flight
      asm volatile("s_waitcnt vmcnt(4)" ::: "memory");  // tile kt landed
    } else {
      asm volatile("s_waitcnt vmcnt(0)" ::: "memory");
    }
    __builtin_amdgcn_s_barrier();  // all waves' buf[cur] staged
    __builtin_amdgcn_sched_barrier(0);

    const unsigned short* Kl = ldsK[cur];
    const unsigned short* Vl = ldsV[cur];

    // S = Q K^T : B-frag B[k=quad*8+j][n=key(lane&15)] from swizzled ldsK
    f32x4 sfr[4];
    __builtin_amdgcn_s_setprio(1);
#pragma unroll
    for (int nt = 0; nt < 4; nt++) {
      int key = nt * 16 + l15;
      bf16x8 kf0 = *(const bf16x8*)&Kl[key * 64 + ((quad ^ (key & 7)) << 3)];
      bf16x8 kf1 = *(const bf16x8*)&Kl[key * 64 + (((4 + quad) ^ (key & 7)) << 3)];
      f32x4 s = {0.f, 0.f, 0.f, 0.f};
      s = __builtin_amdgcn_mfma_f32_16x16x32_bf16(aq0, kf0, s, 0, 0, 0);
      s = __builtin_amdgcn_mfma_f32_16x16x32_bf16(aq1, kf1, s, 0, 0, 0);
      sfr[nt] = s;
    }
    __builtin_amdgcn_s_setprio(0);

    // p = exp2(leaky(S)) (scale pre-folded); accumulate l; P -> LDS (trunc bf16)
#pragma unroll
    for (int nt = 0; nt < 4; nt++) {
      int col = nt * 16 + l15;
#pragma unroll
      for (int reg = 0; reg < 4; reg++) {
        float v = sfr[nt][reg];
        float e = __builtin_amdgcn_exp2f(fmaxf(v, 0.2f * v));
        lsum[reg] += e;
        int row = quad * 4 + reg;  // C-layout: row=(lane>>4)*4+reg, col=lane&15
        Pw[(row << 6) + (((((col >> 3) ^ (row & 7))) << 3) | (col & 7))] =
            (unsigned short)(__builtin_bit_cast(unsigned int, e) >> 16);
      }
    }
    __builtin_amdgcn_s_waitcnt(0xC07F);  // lgkmcnt(0): P writes land before reads

    // O += P V : A-frag from Pw round-trip, B-frag from swizzled ldsV
    __builtin_amdgcn_s_setprio(1);
#pragma unroll
    for (int kc = 0; kc < 2; kc++) {
      bf16x8 ap = *(const bf16x8*)&Pw[(l15 << 6) + ((((kc << 2) + quad) ^ (l15 & 7)) << 3)];
#pragma unroll
      for (int nt = 0; nt < 4; nt++) {
        int d = nt * 16 + l15;
        bf16x8 vf = *(const bf16x8*)&Vl[(d << 6) + ((((kc << 2) + quad) ^ (d & 7)) << 3)];
        o[nt] = __builtin_amdgcn_mfma_f32_16x16x32_bf16(ap, vf, o[nt], 0, 0, 0);
      }
    }
    __builtin_amdgcn_s_setprio(0);
    __builtin_amdgcn_sched_barrier(0);
    __builtin_amdgcn_s_barrier();  // buf[cur] reads done -> next stage may overwrite
  }

  // epilogue: reduce l across the 16 lanes sharing each row group, normalize
  float inv[4];
#pragma unroll
  for (int reg = 0; reg < 4; reg++) {
    float l = lsum[reg];
    l += __shfl_xor(l, 1, 64);
    l += __shfl_xor(l, 2, 64);
    l += __shfl_xor(l, 4, 64);
    l += __shfl_xor(l, 8, 64);
    inv[reg] = 1.0f / l;
  }
  const int b = bh >> 2, head = bh & 3;
#pragma unroll
  for (int nt = 0; nt < 4; nt++) {
    int d = nt * 16 + l15;
#pragma unroll
    for (int reg = 0; reg < 4; reg++) {
      int trow = qtile * 64 + wave * 16 + quad * 4 + reg;
      out[((size_t)b * T_SEQ + trow) * 256 + head * 64 + d] = o[nt][reg] * inv[reg];
    }
  }
}

extern "C" void kernel_launch(void* const* d_in, const int* in_sizes, int n_in,
                              void* d_out, int out_size, void* d_ws, size_t ws_size,
                              hipStream_t stream) {
  const float* h = (const float*)d_in[0];
  const float* W = (const float*)d_in[1];
  float* out = (float*)d_out;
  // workspace: Kb 8 MB + Vt 8 MB + Wt 256 KB (hi/lo bf16 planes of W^T)
  unsigned short* Kb = (unsigned short*)d_ws;
  unsigned short* Vt = Kb + (size_t)32 * T_SEQ * DH;
  unsigned short* Wt = Vt + (size_t)32 * T_SEQ * DH;
  wprep<<<256, 256, 0, stream>>>(W, Wt);
  wh_gemm<<<512, 256, 0, stream>>>(h, Wt, Kb, Vt);
  attn<<<32 * 32, 256, 0, stream>>>(Kb, Vt, out);
}